// Round 1
// baseline (887.700 us; speedup 1.0000x reference)
//
#include <hip/hip_runtime.h>
#include <stdint.h>

#define DD 2048
#define KK 1024
#define NR 16384
#define QSIZE (NR * DD)

typedef _Float16 h8 __attribute__((ext_vector_type(8)));
typedef float f4v __attribute__((ext_vector_type(4)));

__device__ __forceinline__ void ins4(uint64_t p, uint64_t& a, uint64_t& b, uint64_t& c, uint64_t& d) {
  if (p < d) {
    if (p < c) {
      d = c;
      if (p < b) { c = b; if (p < a) { b = a; a = p; } else { b = p; } }
      else { c = p; }
    } else { d = p; }
  }
}

// ---------- P1: codebook prep: E (fp32) -> E16 (fp16), e2[k] = ||e_k||^2 ----------
__global__ __launch_bounds__(256) void prep_kernel(const float* __restrict__ E,
                                                   _Float16* __restrict__ E16,
                                                   float* __restrict__ e2) {
  const int k = blockIdx.x;   // codebook row
  const int t = threadIdx.x;  // 0..255, 8 floats each
  const float4* src = (const float4*)(E + (size_t)k * DD);
  float4 a = src[t * 2 + 0];
  float4 b = src[t * 2 + 1];
  h8 hv;
  hv[0] = (_Float16)a.x; hv[1] = (_Float16)a.y; hv[2] = (_Float16)a.z; hv[3] = (_Float16)a.w;
  hv[4] = (_Float16)b.x; hv[5] = (_Float16)b.y; hv[6] = (_Float16)b.z; hv[7] = (_Float16)b.w;
  ((h8*)E16)[k * 256 + t] = hv;
  float s = a.x * a.x + a.y * a.y + a.z * a.z + a.w * a.w
          + b.x * b.x + b.y * b.y + b.z * b.z + b.w * b.w;
  #pragma unroll
  for (int off = 32; off >= 1; off >>= 1) s += __shfl_xor(s, off);
  __shared__ float part[4];
  if ((t & 63) == 0) part[t >> 6] = s;
  __syncthreads();
  if (t == 0) e2[k] = part[0] + part[1] + part[2] + part[3];
}

// ---------- G: fp16 MFMA GEMM (s = e2 - 2 x.e) fused with per-row top-4 ----------
#define BM 64
#define BN 256
#define BD 64
#define LDA 72  // padded LDS stride in halves (144 B: 16B-aligned, 2-way-bank only)
#define LDB 72

__global__ __launch_bounds__(256, 2) void gemm_top4(
    const float* __restrict__ X, const _Float16* __restrict__ E16,
    const float* __restrict__ e2, uint64_t* __restrict__ top4out)
{
  __shared__ _Float16 As[BM * LDA];          //  9216 B
  __shared__ _Float16 Bs[BN * LDB];          // 36864 B
  __shared__ float    Sv[16 * BN];           // 16384 B  (one 16-row chunk of s-values)
  __shared__ uint64_t Mrg[16 * 16 * 4];      //  8192 B
  __shared__ uint64_t Gtop[BM * 4];          //  2048 B  -> total 72704 B, 2 blocks/CU

  const int t    = threadIdx.x;
  const int lane = t & 63;
  const int wv   = t >> 6;        // 4 waves, each owns a 64x64 sub-tile (4x4 MFMA tiles)
  const int rb   = blockIdx.x >> 1;
  const int kg   = blockIdx.x & 1;  // K-split: each block covers 512 of 1024 cols
  const int row0 = rb * BM;

  Gtop[t] = ~0ull;  // 64 rows x 4 slots, packed (f32bits(s)<<32 | col) keys

  const int ar = t >> 2, aq = t & 3;       // staging: row, quarter
  const int m  = lane & 15, qd = lane >> 4;

  for (int pass = 0; pass < 2; ++pass) {
    const int c0 = kg * 512 + pass * 256;
    f4v acc[4][4];
    #pragma unroll
    for (int i = 0; i < 4; ++i)
      #pragma unroll
      for (int j = 0; j < 4; ++j) {
        f4v z = {0.0f, 0.0f, 0.0f, 0.0f};
        acc[i][j] = z;
      }

    for (int dt = 0; dt < DD / BD; ++dt) {
      const int d0 = dt * BD;
      // stage A: 64 rows x 64 d, fp32 -> fp16 on the fly
      {
        const float4* s4 = (const float4*)(X + (size_t)(row0 + ar) * DD + d0 + aq * 16);
        float4 v0 = s4[0], v1 = s4[1], v2 = s4[2], v3 = s4[3];
        h8 h0, h1;
        h0[0] = (_Float16)v0.x; h0[1] = (_Float16)v0.y; h0[2] = (_Float16)v0.z; h0[3] = (_Float16)v0.w;
        h0[4] = (_Float16)v1.x; h0[5] = (_Float16)v1.y; h0[6] = (_Float16)v1.z; h0[7] = (_Float16)v1.w;
        h1[0] = (_Float16)v2.x; h1[1] = (_Float16)v2.y; h1[2] = (_Float16)v2.z; h1[3] = (_Float16)v2.w;
        h1[4] = (_Float16)v3.x; h1[5] = (_Float16)v3.y; h1[6] = (_Float16)v3.z; h1[7] = (_Float16)v3.w;
        h8* dst = (h8*)(As + ar * LDA + aq * 16);
        dst[0] = h0; dst[1] = h1;
      }
      // stage B: 256 cols x 64 d, already fp16 in ws
      #pragma unroll
      for (int g = 0; g < 4; ++g) {
        const int c = g * 64 + ar;
        const h8* s8 = (const h8*)(E16 + (size_t)(c0 + c) * DD + d0 + aq * 16);
        h8 b0 = s8[0], b1 = s8[1];
        h8* dst = (h8*)(Bs + c * LDB + aq * 16);
        dst[0] = b0; dst[1] = b1;
      }
      __syncthreads();
      #pragma unroll
      for (int ks = 0; ks < 2; ++ks) {
        const int k0 = ks * 32 + qd * 8;
        h8 af[4], bf[4];
        #pragma unroll
        for (int mt = 0; mt < 4; ++mt) af[mt] = *(const h8*)(As + (mt * 16 + m) * LDA + k0);
        #pragma unroll
        for (int nt = 0; nt < 4; ++nt) bf[nt] = *(const h8*)(Bs + (wv * 64 + nt * 16 + m) * LDB + k0);
        #pragma unroll
        for (int mt = 0; mt < 4; ++mt)
          #pragma unroll
          for (int nt = 0; nt < 4; ++nt)
            acc[mt][nt] = __builtin_amdgcn_mfma_f32_16x16x32_f16(af[mt], bf[nt], acc[mt][nt], 0, 0, 0);
      }
      __syncthreads();
    }

    // epilogue: s = e2 - 2*dot (+4096 bias keeps packed-u64 ordering safe), top-4 update
    float e2v[4];
    #pragma unroll
    for (int nt = 0; nt < 4; ++nt) e2v[nt] = e2[c0 + wv * 64 + nt * 16 + m];

    for (int mt = 0; mt < 4; ++mt) {  // 16-row chunks
      #pragma unroll
      for (int nt = 0; nt < 4; ++nt)
        #pragma unroll
        for (int r = 0; r < 4; ++r)
          Sv[(qd * 4 + r) * BN + wv * 64 + nt * 16 + m] =
              e2v[nt] - 2.0f * acc[mt][nt][r] + 4096.0f;  // C/D layout: col=lane&15, row=qd*4+r
      __syncthreads();
      {  // 16 threads per row, each scans 16 cols -> local top-4
        uint64_t t0 = ~0ull, t1 = ~0ull, t2 = ~0ull, t3 = ~0ull;
        const int rl = t >> 4, j = t & 15;
        #pragma unroll
        for (int i = 0; i < 16; ++i) {
          const int cl = j + i * 16;
          const float svv = Sv[rl * BN + cl];
          const uint64_t p = ((uint64_t)__float_as_uint(svv) << 32) | (uint32_t)(c0 + cl);
          ins4(p, t0, t1, t2, t3);
        }
        Mrg[t * 4 + 0] = t0; Mrg[t * 4 + 1] = t1; Mrg[t * 4 + 2] = t2; Mrg[t * 4 + 3] = t3;
      }
      __syncthreads();
      if (t < 16) {  // one thread per row merges 16x4 into the running global top-4
        const int gr = mt * 16 + t;
        uint64_t g0 = Gtop[gr * 4 + 0], g1 = Gtop[gr * 4 + 1];
        uint64_t g2 = Gtop[gr * 4 + 2], g3 = Gtop[gr * 4 + 3];
        for (int i = 0; i < 64; ++i) ins4(Mrg[t * 64 + i], g0, g1, g2, g3);
        Gtop[gr * 4 + 0] = g0; Gtop[gr * 4 + 1] = g1;
        Gtop[gr * 4 + 2] = g2; Gtop[gr * 4 + 3] = g3;
      }
      __syncthreads();
    }
  }
  // 256 entries = 64 rows x 4 slots; thread t -> row t>>2, slot t&3
  top4out[((size_t)(row0 + (t >> 2)) * 2 + kg) * 4 + (t & 3)] = Gtop[t];
}

// ---------- R: fp64 refine of near-tie candidates + gather + index write ----------
__global__ __launch_bounds__(256) void refine_out(
    const float* __restrict__ X, const float* __restrict__ E,
    const uint64_t* __restrict__ top4, float* __restrict__ out)
{
  const int lane = threadIdx.x & 63;
  const int wv   = threadIdx.x >> 6;
  const int row  = blockIdx.x * 4 + wv;  // one wave per row

  uint64_t kbest = ~0ull;
  float sv[8];
  uint64_t kk[8];
  #pragma unroll
  for (int j = 0; j < 8; ++j) {
    kk[j] = top4[(size_t)row * 8 + j];
    sv[j] = __uint_as_float((uint32_t)(kk[j] >> 32));
    if (kk[j] < kbest) kbest = kk[j];
  }
  const float smin = __uint_as_float((uint32_t)(kbest >> 32));
  int nsurv = 0;
  #pragma unroll
  for (int j = 0; j < 8; ++j) nsurv += (sv[j] <= smin + 4.0f) ? 1 : 0;
  int bestc = (int)(uint32_t)(kbest & 0xffffffffu);

  if (nsurv > 1) {  // wave-uniform branch: exact fp64 re-rank of survivors
    float xv[32];
    #pragma unroll
    for (int i = 0; i < 32; ++i) xv[i] = X[(size_t)row * DD + lane + 64 * i];
    double bestd = 1e300;
    int bcol = 0x7fffffff;
    for (int j = 0; j < 8; ++j) {
      if (sv[j] > smin + 4.0f) continue;
      const int c = (int)(uint32_t)(kk[j] & 0xffffffffu);
      const float* er = E + (size_t)c * DD;
      double a = 0.0;
      #pragma unroll
      for (int i = 0; i < 32; ++i) {
        const double dif = (double)xv[i] - (double)er[lane + 64 * i];
        a += dif * dif;
      }
      #pragma unroll
      for (int off = 32; off >= 1; off >>= 1) a += __shfl_xor(a, off);
      if (a < bestd || (a == bestd && c < bcol)) { bestd = a; bcol = c; }  // numpy first-index tiebreak
    }
    bestc = bcol;
  }

  const f4v* esrc = (const f4v*)(E + (size_t)bestc * DD);
  f4v* dst = (f4v*)out + (size_t)row * (DD / 4);
  #pragma unroll
  for (int i = 0; i < 8; ++i) dst[lane + 64 * i] = esrc[lane + 64 * i];
  if (lane == 0) out[(size_t)QSIZE + row] = (float)bestc;
}

extern "C" void kernel_launch(void* const* d_in, const int* in_sizes, int n_in,
                              void* d_out, int out_size, void* d_ws, size_t ws_size,
                              hipStream_t stream) {
  const float* X = (const float*)d_in[0];  // [16384, 2048] fp32
  const float* E = (const float*)d_in[1];  // [1024, 2048] fp32
  float* out = (float*)d_out;              // quantize (33.5M) then indices (16384) as float
  char* ws = (char*)d_ws;
  _Float16* E16 = (_Float16*)ws;                      // 4 MB
  float*    e2  = (float*)(ws + 4194304);             // 4 KB
  uint64_t* top4 = (uint64_t*)(ws + 4194304 + 4096);  // 1 MB: [16384][2 kgroups][4]

  prep_kernel<<<KK, 256, 0, stream>>>(E, E16, e2);
  gemm_top4<<<512, 256, 0, stream>>>(X, E16, e2, top4);
  refine_out<<<4096, 256, 0, stream>>>(X, E, top4, out);
}

// Round 2
// 640.889 us; speedup vs baseline: 1.3851x; 1.3851x over previous
//
#include <hip/hip_runtime.h>
#include <stdint.h>

#define DD 2048
#define KK 1024
#define NR 16384
#define QSIZE (NR * DD)

typedef _Float16 h8 __attribute__((ext_vector_type(8)));
typedef float f4v __attribute__((ext_vector_type(4)));

__device__ __forceinline__ void ins4(uint64_t p, uint64_t& a, uint64_t& b, uint64_t& c, uint64_t& d) {
  if (p < d) {
    if (p < c) {
      d = c;
      if (p < b) { c = b; if (p < a) { b = a; a = p; } else { b = p; } }
      else { c = p; }
    } else { d = p; }
  }
}

// ---------- P1: codebook prep: E (fp32) -> E16 (fp16), e2[k] = ||e_k||^2 ----------
__global__ __launch_bounds__(256) void prep_kernel(const float* __restrict__ E,
                                                   _Float16* __restrict__ E16,
                                                   float* __restrict__ e2) {
  const int k = blockIdx.x;   // codebook row
  const int t = threadIdx.x;  // 0..255, 8 floats each
  const float4* src = (const float4*)(E + (size_t)k * DD);
  float4 a = src[t * 2 + 0];
  float4 b = src[t * 2 + 1];
  h8 hv;
  hv[0] = (_Float16)a.x; hv[1] = (_Float16)a.y; hv[2] = (_Float16)a.z; hv[3] = (_Float16)a.w;
  hv[4] = (_Float16)b.x; hv[5] = (_Float16)b.y; hv[6] = (_Float16)b.z; hv[7] = (_Float16)b.w;
  ((h8*)E16)[k * 256 + t] = hv;
  float s = a.x * a.x + a.y * a.y + a.z * a.z + a.w * a.w
          + b.x * b.x + b.y * b.y + b.z * b.z + b.w * b.w;
  #pragma unroll
  for (int off = 32; off >= 1; off >>= 1) s += __shfl_xor(s, off);
  __shared__ float part[4];
  if ((t & 63) == 0) part[t >> 6] = s;
  __syncthreads();
  if (t == 0) e2[k] = part[0] + part[1] + part[2] + part[3];
}

// ---------- G: fp16 MFMA GEMM (s = e2 - 2 x.e) fused with per-row top-4 ----------
#define BM 64
#define BN 256
#define BD 64
#define LDA 72  // padded LDS stride in halves (144 B: 16B-aligned, 2-way-bank only)
#define LDB 72

__global__ __launch_bounds__(256, 3) void gemm_top4(
    const float* __restrict__ X, const _Float16* __restrict__ E16,
    const float* __restrict__ e2, uint64_t* __restrict__ top4out)
{
  __shared__ _Float16 As[BM * LDA];          //  9216 B
  // Bs (staging) and the epilogue buffers are never live simultaneously
  // (barrier-separated) -> overlay them. 36864 B total.
  __shared__ union {
    _Float16 Bs[BN * LDB];                   // 36864 B
    struct {
      float    Sv[16 * BN];                  // 16384 B
      uint64_t Mrg[16 * 16 * 4];             //  8192 B
    } ep;
  } U;
  __shared__ uint64_t Gtop[BM * 4];          //  2048 B -> total 48128 B, 3 blocks/CU

  const int t    = threadIdx.x;
  const int lane = t & 63;
  const int wv   = t >> 6;        // 4 waves, each owns a 64x64 sub-tile (4x4 MFMA tiles)
  const int rb   = blockIdx.x >> 1;
  const int kg   = blockIdx.x & 1;  // K-split: each block covers 512 of 1024 cols
  const int row0 = rb * BM;

  Gtop[t] = ~0ull;  // 64 rows x 4 slots, packed (f32bits(s)<<32 | col) keys

  const int ar = t >> 2, aq = t & 3;       // staging: row, quarter
  const int m  = lane & 15, qd = lane >> 4;

  for (int pass = 0; pass < 2; ++pass) {
    const int c0 = kg * 512 + pass * 256;
    f4v acc[4][4];
    #pragma unroll
    for (int i = 0; i < 4; ++i)
      #pragma unroll
      for (int j = 0; j < 4; ++j) {
        f4v z = {0.0f, 0.0f, 0.0f, 0.0f};
        acc[i][j] = z;
      }

    for (int dt = 0; dt < DD / BD; ++dt) {
      const int d0 = dt * BD;
      // stage A: 64 rows x 64 d, fp32 -> fp16 on the fly
      {
        const float4* s4 = (const float4*)(X + (size_t)(row0 + ar) * DD + d0 + aq * 16);
        float4 v0 = s4[0], v1 = s4[1], v2 = s4[2], v3 = s4[3];
        h8 h0, h1;
        h0[0] = (_Float16)v0.x; h0[1] = (_Float16)v0.y; h0[2] = (_Float16)v0.z; h0[3] = (_Float16)v0.w;
        h0[4] = (_Float16)v1.x; h0[5] = (_Float16)v1.y; h0[6] = (_Float16)v1.z; h0[7] = (_Float16)v1.w;
        h1[0] = (_Float16)v2.x; h1[1] = (_Float16)v2.y; h1[2] = (_Float16)v2.z; h1[3] = (_Float16)v2.w;
        h1[4] = (_Float16)v3.x; h1[5] = (_Float16)v3.y; h1[6] = (_Float16)v3.z; h1[7] = (_Float16)v3.w;
        h8* dst = (h8*)(As + ar * LDA + aq * 16);
        dst[0] = h0; dst[1] = h1;
      }
      // stage B: 256 cols x 64 d, already fp16 in ws
      #pragma unroll
      for (int g = 0; g < 4; ++g) {
        const int c = g * 64 + ar;
        const h8* s8 = (const h8*)(E16 + (size_t)(c0 + c) * DD + d0 + aq * 16);
        h8 b0 = s8[0], b1 = s8[1];
        h8* dst = (h8*)(U.Bs + c * LDB + aq * 16);
        dst[0] = b0; dst[1] = b1;
      }
      __syncthreads();
      #pragma unroll
      for (int ks = 0; ks < 2; ++ks) {
        const int k0 = ks * 32 + qd * 8;
        h8 af[4], bf[4];
        #pragma unroll
        for (int mt = 0; mt < 4; ++mt) af[mt] = *(const h8*)(As + (mt * 16 + m) * LDA + k0);
        #pragma unroll
        for (int nt = 0; nt < 4; ++nt) bf[nt] = *(const h8*)(U.Bs + (wv * 64 + nt * 16 + m) * LDB + k0);
        #pragma unroll
        for (int mt = 0; mt < 4; ++mt)
          #pragma unroll
          for (int nt = 0; nt < 4; ++nt)
            acc[mt][nt] = __builtin_amdgcn_mfma_f32_16x16x32_f16(af[mt], bf[nt], acc[mt][nt], 0, 0, 0);
      }
      __syncthreads();
    }

    // epilogue: s = e2 - 2*dot (+4096 bias keeps packed-u64 ordering safe), top-4 update.
    // MUST be fully unrolled: dynamic acc[mt] indexing would spill the
    // accumulators to scratch (R1: 1.7 GB WRITE_SIZE, 710 us, MfmaUtil 0.5%).
    float e2v[4];
    #pragma unroll
    for (int nt = 0; nt < 4; ++nt) e2v[nt] = e2[c0 + wv * 64 + nt * 16 + m];

    #pragma unroll
    for (int mt = 0; mt < 4; ++mt) {  // 16-row chunks
      #pragma unroll
      for (int nt = 0; nt < 4; ++nt)
        #pragma unroll
        for (int r = 0; r < 4; ++r)
          U.ep.Sv[(qd * 4 + r) * BN + wv * 64 + nt * 16 + m] =
              e2v[nt] - 2.0f * acc[mt][nt][r] + 4096.0f;  // C/D layout: col=lane&15, row=qd*4+r
      __syncthreads();
      {  // 16 threads per row, each scans 16 cols -> local top-4
        uint64_t t0 = ~0ull, t1 = ~0ull, t2 = ~0ull, t3 = ~0ull;
        const int rl = t >> 4, j = t & 15;
        #pragma unroll
        for (int i = 0; i < 16; ++i) {
          const int cl = j + i * 16;
          const float svv = U.ep.Sv[rl * BN + cl];
          const uint64_t p = ((uint64_t)__float_as_uint(svv) << 32) | (uint32_t)(c0 + cl);
          ins4(p, t0, t1, t2, t3);
        }
        U.ep.Mrg[t * 4 + 0] = t0; U.ep.Mrg[t * 4 + 1] = t1;
        U.ep.Mrg[t * 4 + 2] = t2; U.ep.Mrg[t * 4 + 3] = t3;
      }
      __syncthreads();
      if (t < 16) {  // one thread per row merges 16x4 into the running global top-4
        const int gr = mt * 16 + t;
        uint64_t g0 = Gtop[gr * 4 + 0], g1 = Gtop[gr * 4 + 1];
        uint64_t g2 = Gtop[gr * 4 + 2], g3 = Gtop[gr * 4 + 3];
        for (int i = 0; i < 64; ++i) ins4(U.ep.Mrg[t * 64 + i], g0, g1, g2, g3);
        Gtop[gr * 4 + 0] = g0; Gtop[gr * 4 + 1] = g1;
        Gtop[gr * 4 + 2] = g2; Gtop[gr * 4 + 3] = g3;
      }
      __syncthreads();
    }
  }
  // 256 entries = 64 rows x 4 slots; thread t -> row t>>2, slot t&3
  top4out[((size_t)(row0 + (t >> 2)) * 2 + kg) * 4 + (t & 3)] = Gtop[t];
}

// ---------- R: fp64 refine of near-tie candidates + gather + index write ----------
__global__ __launch_bounds__(256) void refine_out(
    const float* __restrict__ X, const float* __restrict__ E,
    const uint64_t* __restrict__ top4, float* __restrict__ out)
{
  const int lane = threadIdx.x & 63;
  const int wv   = threadIdx.x >> 6;
  const int row  = blockIdx.x * 4 + wv;  // one wave per row

  uint64_t kbest = ~0ull;
  float sv[8];
  uint64_t kk[8];
  #pragma unroll
  for (int j = 0; j < 8; ++j) {
    kk[j] = top4[(size_t)row * 8 + j];
    sv[j] = __uint_as_float((uint32_t)(kk[j] >> 32));
    if (kk[j] < kbest) kbest = kk[j];
  }
  const float smin = __uint_as_float((uint32_t)(kbest >> 32));
  int nsurv = 0;
  #pragma unroll
  for (int j = 0; j < 8; ++j) nsurv += (sv[j] <= smin + 4.0f) ? 1 : 0;
  int bestc = (int)(uint32_t)(kbest & 0xffffffffu);

  if (nsurv > 1) {  // wave-uniform branch: exact fp64 re-rank of survivors
    float xv[32];
    #pragma unroll
    for (int i = 0; i < 32; ++i) xv[i] = X[(size_t)row * DD + lane + 64 * i];
    double bestd = 1e300;
    int bcol = 0x7fffffff;
    for (int j = 0; j < 8; ++j) {
      if (sv[j] > smin + 4.0f) continue;
      const int c = (int)(uint32_t)(kk[j] & 0xffffffffu);
      const float* er = E + (size_t)c * DD;
      double a = 0.0;
      #pragma unroll
      for (int i = 0; i < 32; ++i) {
        const double dif = (double)xv[i] - (double)er[lane + 64 * i];
        a += dif * dif;
      }
      #pragma unroll
      for (int off = 32; off >= 1; off >>= 1) a += __shfl_xor(a, off);
      if (a < bestd || (a == bestd && c < bcol)) { bestd = a; bcol = c; }  // numpy first-index tiebreak
    }
    bestc = bcol;
  }

  const f4v* esrc = (const f4v*)(E + (size_t)bestc * DD);
  f4v* dst = (f4v*)out + (size_t)row * (DD / 4);
  #pragma unroll
  for (int i = 0; i < 8; ++i) dst[lane + 64 * i] = esrc[lane + 64 * i];
  if (lane == 0) out[(size_t)QSIZE + row] = (float)bestc;
}

extern "C" void kernel_launch(void* const* d_in, const int* in_sizes, int n_in,
                              void* d_out, int out_size, void* d_ws, size_t ws_size,
                              hipStream_t stream) {
  const float* X = (const float*)d_in[0];  // [16384, 2048] fp32
  const float* E = (const float*)d_in[1];  // [1024, 2048] fp32
  float* out = (float*)d_out;              // quantize (33.5M) then indices (16384) as float
  char* ws = (char*)d_ws;
  _Float16* E16 = (_Float16*)ws;                      // 4 MB
  float*    e2  = (float*)(ws + 4194304);             // 4 KB
  uint64_t* top4 = (uint64_t*)(ws + 4194304 + 4096);  // 1 MB: [16384][2 kgroups][4]

  prep_kernel<<<KK, 256, 0, stream>>>(E, E16, e2);
  gemm_top4<<<512, 256, 0, stream>>>(X, E16, e2, top4);
  refine_out<<<4096, 256, 0, stream>>>(X, E, top4, out);
}

// Round 3
// 450.623 us; speedup vs baseline: 1.9699x; 1.4222x over previous
//
#include <hip/hip_runtime.h>
#include <stdint.h>

#define DD 2048
#define KK 1024
#define NR 16384
#define QSIZE (NR * DD)
#define MARGIN 4.0f

typedef _Float16 h8 __attribute__((ext_vector_type(8)));
typedef float f4v __attribute__((ext_vector_type(4)));

typedef __attribute__((address_space(3))) uint32_t lds_u32;
typedef const __attribute__((address_space(1))) uint32_t glb_u32;

__device__ __forceinline__ void async16(const _Float16* g, _Float16* l) {
  __builtin_amdgcn_global_load_lds((glb_u32*)g, (lds_u32*)l, 16, 0, 0);
}

__device__ __forceinline__ void ins4(uint64_t p, uint64_t& a, uint64_t& b, uint64_t& c, uint64_t& d) {
  if (p < d) {
    if (p < c) {
      d = c;
      if (p < b) { c = b; if (p < a) { b = a; a = p; } else { b = p; } }
      else { c = p; }
    } else { d = p; }
  }
}

// ---------- C0: X fp32 -> fp16 ----------
__global__ __launch_bounds__(256) void cvt_x(const float* __restrict__ X,
                                             _Float16* __restrict__ X16) {
  const size_t i = ((size_t)blockIdx.x * 256 + threadIdx.x) * 8;
  float4 a = *(const float4*)(X + i);
  float4 b = *(const float4*)(X + i + 4);
  h8 h;
  h[0] = (_Float16)a.x; h[1] = (_Float16)a.y; h[2] = (_Float16)a.z; h[3] = (_Float16)a.w;
  h[4] = (_Float16)b.x; h[5] = (_Float16)b.y; h[6] = (_Float16)b.z; h[7] = (_Float16)b.w;
  *(h8*)(X16 + i) = h;
}

// ---------- P1: codebook prep: E -> E16 + e2 ----------
__global__ __launch_bounds__(256) void prep_kernel(const float* __restrict__ E,
                                                   _Float16* __restrict__ E16,
                                                   float* __restrict__ e2) {
  const int k = blockIdx.x;
  const int t = threadIdx.x;
  const float4* src = (const float4*)(E + (size_t)k * DD);
  float4 a = src[t * 2 + 0];
  float4 b = src[t * 2 + 1];
  h8 hv;
  hv[0] = (_Float16)a.x; hv[1] = (_Float16)a.y; hv[2] = (_Float16)a.z; hv[3] = (_Float16)a.w;
  hv[4] = (_Float16)b.x; hv[5] = (_Float16)b.y; hv[6] = (_Float16)b.z; hv[7] = (_Float16)b.w;
  ((h8*)E16)[k * 256 + t] = hv;
  float s = a.x * a.x + a.y * a.y + a.z * a.z + a.w * a.w
          + b.x * b.x + b.y * b.y + b.z * b.z + b.w * b.w;
  #pragma unroll
  for (int off = 32; off >= 1; off >>= 1) s += __shfl_xor(s, off);
  __shared__ float part[4];
  if ((t & 63) == 0) part[t >> 6] = s;
  __syncthreads();
  if (t == 0) e2[k] = part[0] + part[1] + part[2] + part[3];
}

// ---------- G-big: m97-style fp16 MFMA GEMM + per-row top-4 ----------
// 128x128 tile, BK=64, global_load_lds(16B) staging, XOR-swizzled LDS chunks.
__global__ __launch_bounds__(256, 3) void gemm_big(
    const _Float16* __restrict__ X16, const _Float16* __restrict__ E16,
    const float* __restrict__ e2, uint64_t* __restrict__ top4out)
{
  __shared__ union {
    struct { __align__(16) _Float16 As[8192]; __align__(16) _Float16 Bs[8192]; } st;  // 32768 B
    struct { float Sv[2][16][132]; uint64_t Mrg[32][33]; } ep;                        // 25344 B
  } U;
  __shared__ uint64_t Gtop[512];  // 128 rows x 4 slots -> total LDS 36864 B, 3-4 blk/CU

  const int t    = threadIdx.x;
  const int lane = t & 63;
  const int wv   = t >> 6;
  const int wr   = wv >> 1, wc = wv & 1;   // wave quadrant of the 128x128 tile
  const int m    = lane & 15, qd = lane >> 4;
  const int rt   = blockIdx.x & 127;       // row-tile; all 8 col-groups of rt share XCD rt%8
  const int cg   = blockIdx.x >> 7;        // col-group (128 cols each)
  const int row0 = rt * 128, col0 = cg * 128;

  Gtop[t] = ~0ull; Gtop[t + 256] = ~0ull;

  // staging geometry: thread t covers row rstg (of 32-row group i), 16B chunk cstg,
  // XOR-swizzled so ds_read_b128 fragments are conflict-free.
  const int rstg = t >> 3, cstg = t & 7;
  const int cswz = cstg ^ (rstg & 7);
  const _Float16* ga = X16 + (size_t)(row0 + rstg) * DD + cswz * 8;
  const _Float16* gb = E16 + (size_t)(col0 + rstg) * DD + cswz * 8;
  _Float16* la = U.st.As + t * 8;
  _Float16* lb = U.st.Bs + t * 8;

  f4v acc[4][4];
  #pragma unroll
  for (int i = 0; i < 4; ++i)
    #pragma unroll
    for (int j = 0; j < 4; ++j) {
      f4v z = {0.0f, 0.0f, 0.0f, 0.0f};
      acc[i][j] = z;
    }

  for (int dt = 0; dt < 32; ++dt) {
    #pragma unroll
    for (int i = 0; i < 4; ++i) async16(ga + (size_t)i * 32 * DD, la + i * 2048);
    #pragma unroll
    for (int i = 0; i < 4; ++i) async16(gb + (size_t)i * 32 * DD, lb + i * 2048);
    ga += 64; gb += 64;
    __syncthreads();
    #pragma unroll
    for (int ks = 0; ks < 2; ++ks) {
      const int sz = ks * 4 + qd;  // which 16B k-chunk this quarter needs
      h8 af[4], bf[4];
      #pragma unroll
      for (int mt = 0; mt < 4; ++mt)
        af[mt] = *(const h8*)(U.st.As + (wr * 64 + mt * 16 + m) * 64 + (sz ^ (m & 7)) * 8);
      #pragma unroll
      for (int nt = 0; nt < 4; ++nt)
        bf[nt] = *(const h8*)(U.st.Bs + (wc * 64 + nt * 16 + m) * 64 + (sz ^ (m & 7)) * 8);
      #pragma unroll
      for (int mt = 0; mt < 4; ++mt)
        #pragma unroll
        for (int nt = 0; nt < 4; ++nt)
          acc[mt][nt] = __builtin_amdgcn_mfma_f32_16x16x32_f16(af[mt], bf[nt], acc[mt][nt], 0, 0, 0);
    }
    __syncthreads();
  }

  // epilogue: s = e2 - 2*dot + 4096 (positive -> packed-u64 order == float order)
  float e2v[4];
  #pragma unroll
  for (int nt = 0; nt < 4; ++nt) e2v[nt] = e2[col0 + wc * 64 + nt * 16 + m];

  #pragma unroll
  for (int mt = 0; mt < 4; ++mt) {  // one 16-row chunk per wr half (32 rows/step)
    #pragma unroll
    for (int nt = 0; nt < 4; ++nt)
      #pragma unroll
      for (int r = 0; r < 4; ++r)
        U.ep.Sv[wr][qd * 4 + r][wc * 64 + nt * 16 + m] =
            e2v[nt] - 2.0f * acc[mt][nt][r] + 4096.0f;  // C/D: col=lane&15, row=qd*4+r
    __syncthreads();
    {  // 8 scanners per row, 16 cols each -> local top-4
      const int row32 = t >> 3, j = t & 7;
      const int wrs = row32 >> 4, rloc = row32 & 15;
      uint64_t t0 = ~0ull, t1 = ~0ull, t2 = ~0ull, t3 = ~0ull;
      #pragma unroll
      for (int i = 0; i < 16; ++i) {
        const int cl = j + i * 8;
        const uint64_t p =
            ((uint64_t)__float_as_uint(U.ep.Sv[wrs][rloc][cl]) << 32) | (uint32_t)(col0 + cl);
        ins4(p, t0, t1, t2, t3);
      }
      U.ep.Mrg[row32][j * 4 + 0] = t0; U.ep.Mrg[row32][j * 4 + 1] = t1;
      U.ep.Mrg[row32][j * 4 + 2] = t2; U.ep.Mrg[row32][j * 4 + 3] = t3;
    }
    __syncthreads();
    if (t < 32) {  // one thread per row merges 8x4 candidates
      const int gr = (t >> 4) * 64 + mt * 16 + (t & 15);
      uint64_t g0 = Gtop[gr * 4 + 0], g1 = Gtop[gr * 4 + 1];
      uint64_t g2 = Gtop[gr * 4 + 2], g3 = Gtop[gr * 4 + 3];
      #pragma unroll
      for (int i = 0; i < 32; ++i) ins4(U.ep.Mrg[t][i], g0, g1, g2, g3);
      Gtop[gr * 4 + 0] = g0; Gtop[gr * 4 + 1] = g1;
      Gtop[gr * 4 + 2] = g2; Gtop[gr * 4 + 3] = g3;
    }
    __syncthreads();
  }

  #pragma unroll
  for (int e = 0; e < 2; ++e) {
    const int idx = t + e * 256;
    const int r = idx >> 2, slot = idx & 3;
    top4out[(size_t)(row0 + r) * 32 + cg * 4 + slot] = Gtop[idx];
  }
}

// ---------- G-small: R2 fallback (if ws too small for X16) ----------
#define BM 64
#define BN 256
#define BD 64
#define LDA 72
#define LDB 72

__global__ __launch_bounds__(256, 3) void gemm_top4(
    const float* __restrict__ X, const _Float16* __restrict__ E16,
    const float* __restrict__ e2, uint64_t* __restrict__ top4out)
{
  __shared__ _Float16 As[BM * LDA];
  __shared__ union {
    _Float16 Bs[BN * LDB];
    struct { float Sv[16 * BN]; uint64_t Mrg[16 * 16 * 4]; } ep;
  } U;
  __shared__ uint64_t Gtop[BM * 4];

  const int t    = threadIdx.x;
  const int lane = t & 63;
  const int wv   = t >> 6;
  const int rb   = blockIdx.x >> 1;
  const int kg   = blockIdx.x & 1;
  const int row0 = rb * BM;

  Gtop[t] = ~0ull;

  const int ar = t >> 2, aq = t & 3;
  const int m  = lane & 15, qd = lane >> 4;

  for (int pass = 0; pass < 2; ++pass) {
    const int c0 = kg * 512 + pass * 256;
    f4v acc[4][4];
    #pragma unroll
    for (int i = 0; i < 4; ++i)
      #pragma unroll
      for (int j = 0; j < 4; ++j) {
        f4v z = {0.0f, 0.0f, 0.0f, 0.0f};
        acc[i][j] = z;
      }

    for (int dt = 0; dt < DD / BD; ++dt) {
      const int d0 = dt * BD;
      {
        const float4* s4 = (const float4*)(X + (size_t)(row0 + ar) * DD + d0 + aq * 16);
        float4 v0 = s4[0], v1 = s4[1], v2 = s4[2], v3 = s4[3];
        h8 h0, h1;
        h0[0] = (_Float16)v0.x; h0[1] = (_Float16)v0.y; h0[2] = (_Float16)v0.z; h0[3] = (_Float16)v0.w;
        h0[4] = (_Float16)v1.x; h0[5] = (_Float16)v1.y; h0[6] = (_Float16)v1.z; h0[7] = (_Float16)v1.w;
        h1[0] = (_Float16)v2.x; h1[1] = (_Float16)v2.y; h1[2] = (_Float16)v2.z; h1[3] = (_Float16)v2.w;
        h1[4] = (_Float16)v3.x; h1[5] = (_Float16)v3.y; h1[6] = (_Float16)v3.z; h1[7] = (_Float16)v3.w;
        h8* dst = (h8*)(As + ar * LDA + aq * 16);
        dst[0] = h0; dst[1] = h1;
      }
      #pragma unroll
      for (int g = 0; g < 4; ++g) {
        const int c = g * 64 + ar;
        const h8* s8 = (const h8*)(E16 + (size_t)(c0 + c) * DD + d0 + aq * 16);
        h8 b0 = s8[0], b1 = s8[1];
        h8* dst = (h8*)(U.Bs + c * LDB + aq * 16);
        dst[0] = b0; dst[1] = b1;
      }
      __syncthreads();
      #pragma unroll
      for (int ks = 0; ks < 2; ++ks) {
        const int k0 = ks * 32 + qd * 8;
        h8 af[4], bf[4];
        #pragma unroll
        for (int mt = 0; mt < 4; ++mt) af[mt] = *(const h8*)(As + (mt * 16 + m) * LDA + k0);
        #pragma unroll
        for (int nt = 0; nt < 4; ++nt) bf[nt] = *(const h8*)(U.Bs + (wv * 64 + nt * 16 + m) * LDB + k0);
        #pragma unroll
        for (int mt = 0; mt < 4; ++mt)
          #pragma unroll
          for (int nt = 0; nt < 4; ++nt)
            acc[mt][nt] = __builtin_amdgcn_mfma_f32_16x16x32_f16(af[mt], bf[nt], acc[mt][nt], 0, 0, 0);
      }
      __syncthreads();
    }

    float e2v[4];
    #pragma unroll
    for (int nt = 0; nt < 4; ++nt) e2v[nt] = e2[c0 + wv * 64 + nt * 16 + m];

    #pragma unroll
    for (int mt = 0; mt < 4; ++mt) {
      #pragma unroll
      for (int nt = 0; nt < 4; ++nt)
        #pragma unroll
        for (int r = 0; r < 4; ++r)
          U.ep.Sv[(qd * 4 + r) * BN + wv * 64 + nt * 16 + m] =
              e2v[nt] - 2.0f * acc[mt][nt][r] + 4096.0f;
      __syncthreads();
      {
        uint64_t t0 = ~0ull, t1 = ~0ull, t2 = ~0ull, t3 = ~0ull;
        const int rl = t >> 4, j = t & 15;
        #pragma unroll
        for (int i = 0; i < 16; ++i) {
          const int cl = j + i * 16;
          const float svv = U.ep.Sv[rl * BN + cl];
          const uint64_t p = ((uint64_t)__float_as_uint(svv) << 32) | (uint32_t)(c0 + cl);
          ins4(p, t0, t1, t2, t3);
        }
        U.ep.Mrg[t * 4 + 0] = t0; U.ep.Mrg[t * 4 + 1] = t1;
        U.ep.Mrg[t * 4 + 2] = t2; U.ep.Mrg[t * 4 + 3] = t3;
      }
      __syncthreads();
      if (t < 16) {
        const int gr = mt * 16 + t;
        uint64_t g0 = Gtop[gr * 4 + 0], g1 = Gtop[gr * 4 + 1];
        uint64_t g2 = Gtop[gr * 4 + 2], g3 = Gtop[gr * 4 + 3];
        for (int i = 0; i < 64; ++i) ins4(U.ep.Mrg[t * 64 + i], g0, g1, g2, g3);
        Gtop[gr * 4 + 0] = g0; Gtop[gr * 4 + 1] = g1;
        Gtop[gr * 4 + 2] = g2; Gtop[gr * 4 + 3] = g3;
      }
      __syncthreads();
    }
  }
  top4out[((size_t)(row0 + (t >> 2)) * 2 + kg) * 4 + (t & 3)] = Gtop[t];
}

// ---------- R: fp64 refine of near-tie candidates + gather + index write ----------
__global__ __launch_bounds__(256) void refine_out(
    const float* __restrict__ X, const float* __restrict__ E,
    const uint64_t* __restrict__ top4, float* __restrict__ out, int nk)
{
  const int lane = threadIdx.x & 63;
  const int wvv  = threadIdx.x >> 6;
  const int row  = blockIdx.x * 4 + wvv;  // one wave per row

  uint64_t mykey = (lane < nk) ? top4[(size_t)row * nk + lane] : ~0ull;
  uint64_t kmin = mykey;
  #pragma unroll
  for (int off = 32; off >= 1; off >>= 1) {
    uint64_t o = (uint64_t)__shfl_xor((unsigned long long)kmin, off);
    if (o < kmin) kmin = o;
  }
  const float smin = __uint_as_float((uint32_t)(kmin >> 32));
  const float mysv = __uint_as_float((uint32_t)(mykey >> 32));
  unsigned long long ball = __ballot(mysv <= smin + MARGIN);  // NaN (pad lanes) excluded
  int bestc = (int)(uint32_t)(kmin & 0xffffffffu);

  if (__popcll(ball) > 1) {  // wave-uniform: exact fp64 re-rank of survivors
    float xv[32];
    #pragma unroll
    for (int i = 0; i < 32; ++i) xv[i] = X[(size_t)row * DD + lane + 64 * i];
    double bestd = 1e300;
    int bcol = 0x7fffffff;
    unsigned long long mm = ball;
    while (mm) {
      const int src = __ffsll((unsigned long long)mm) - 1;
      mm &= mm - 1;
      const int c = (int)(uint32_t)((uint64_t)__shfl((unsigned long long)mykey, src) & 0xffffffffu);
      const float* er = E + (size_t)c * DD;
      double a = 0.0;
      #pragma unroll
      for (int i = 0; i < 32; ++i) {
        const double dif = (double)xv[i] - (double)er[lane + 64 * i];
        a += dif * dif;
      }
      #pragma unroll
      for (int off = 32; off >= 1; off >>= 1) a += __shfl_xor(a, off);
      if (a < bestd || (a == bestd && c < bcol)) { bestd = a; bcol = c; }  // numpy first-index
    }
    bestc = bcol;
  }

  const f4v* esrc = (const f4v*)(E + (size_t)bestc * DD);
  f4v* dst = (f4v*)out + (size_t)row * (DD / 4);
  #pragma unroll
  for (int i = 0; i < 8; ++i) dst[lane + 64 * i] = esrc[lane + 64 * i];
  if (lane == 0) out[(size_t)QSIZE + row] = (float)bestc;
}

extern "C" void kernel_launch(void* const* d_in, const int* in_sizes, int n_in,
                              void* d_out, int out_size, void* d_ws, size_t ws_size,
                              hipStream_t stream) {
  const float* X = (const float*)d_in[0];  // [16384, 2048] fp32
  const float* E = (const float*)d_in[1];  // [1024, 2048] fp32
  float* out = (float*)d_out;
  char* ws = (char*)d_ws;

  _Float16* E16 = (_Float16*)ws;                 // 4 MB
  float*    e2  = (float*)(ws + 4194304);        // 4 KB

  // big path: X16 (67 MB) + top4[16384][8 groups][4] (4 MB)
  const size_t off_x16  = 4194304 + 4096;
  const size_t off_top4 = off_x16 + (size_t)NR * DD * 2;
  const size_t need_big = off_top4 + (size_t)NR * 32 * 8;

  prep_kernel<<<KK, 256, 0, stream>>>(E, E16, e2);
  if (ws_size >= need_big) {
    _Float16* X16 = (_Float16*)(ws + off_x16);
    uint64_t* top4 = (uint64_t*)(ws + off_top4);
    cvt_x<<<NR * DD / (256 * 8), 256, 0, stream>>>(X, X16);
    gemm_big<<<1024, 256, 0, stream>>>(X16, E16, e2, top4);
    refine_out<<<4096, 256, 0, stream>>>(X, E, top4, out, 32);
  } else {
    uint64_t* top4 = (uint64_t*)(ws + off_x16);  // 1 MB fallback layout [row][2][4]
    gemm_top4<<<512, 256, 0, stream>>>(X, E16, e2, top4);
    refine_out<<<4096, 256, 0, stream>>>(X, E, top4, out, 8);
  }
}